// Round 1
// baseline (199.742 us; speedup 1.0000x reference)
//
#include <hip/hip_runtime.h>
#include <math.h>

#define B 2
#define C_IN 256
#define CMID 64
#define CENC 100
#define NPX 4096          // 64*64 low-res pixels per batch
#define H2 128
#define W2 128

__device__ __forceinline__ float bn_apply(float x, float g, float bt, float m, float v) {
    float inv = g * rsqrtf(v + 1e-5f);
    return x * inv + (bt - m * inv);
}

// K1: 1x1 conv (256->64) + BN + ReLU.  grid (128,2), block 256.
// wave = 64 consecutive pixels x 1 co-group (8 co) -> wave-uniform weight index -> s_load.
__global__ __launch_bounds__(256) void k1_conv1x1(
    const float* __restrict__ X, const float* __restrict__ w,
    const float* __restrict__ g, const float* __restrict__ bt,
    const float* __restrict__ m, const float* __restrict__ var,
    float* __restrict__ mid)
{
    int tid = threadIdx.x;
    int p = blockIdx.x * 64 + (tid & 63);           // 0..8191
    int cog = __builtin_amdgcn_readfirstlane(blockIdx.y * 4 + (tid >> 6));
    int co0 = cog * 8;                              // 8 co per thread
    int bb = p >> 12;
    int sp = p & (NPX - 1);
    const float* xp = X + (size_t)bb * C_IN * NPX + sp;
    const float* wp = w + co0 * C_IN;
    float acc[8];
    #pragma unroll
    for (int j = 0; j < 8; ++j) acc[j] = 0.f;
    #pragma unroll 4
    for (int ci = 0; ci < C_IN; ++ci) {
        float x = xp[(size_t)ci * NPX];
        #pragma unroll
        for (int j = 0; j < 8; ++j) acc[j] += x * wp[j * C_IN + ci];
    }
    float* op = mid + (size_t)bb * CMID * NPX + co0 * NPX + sp;
    #pragma unroll
    for (int j = 0; j < 8; ++j) {
        int co = co0 + j;
        float y = bn_apply(acc[j], g[co], bt[co], m[co], var[co]);
        op[j * NPX] = fmaxf(y, 0.f);
    }
}

// K2a: 3x3 conv (64->100), pad 1, partial over ci (split 4), atomicAdd into enc.
// grid (128 tiles, 4 ci-splits), block 256 = 64 px (8x8) x 4 subpos-waves.
// Each thread computes the 25 out-channels {4k+s} for its pixel.
__global__ __launch_bounds__(256) void k2a_conv3x3(
    const float* __restrict__ mid, const float* __restrict__ ew,
    float* __restrict__ enc)
{
    __shared__ float mt[16 * 100];   // 16 ci x 10x10 halo tile, 6.4 KB
    int tid = threadIdx.x;
    int bx = blockIdx.x;
    int bb = bx >> 6;                // batch
    int t = bx & 63;
    int ty0 = (t >> 3) * 8, tx0 = (t & 7) * 8;
    int cib = blockIdx.y * 16;
    for (int idx = tid; idx < 1600; idx += 256) {
        int ci = idx / 100;
        int rem = idx - ci * 100;
        int r = rem / 10, cc = rem - r * 10;
        int gy = ty0 + r - 1, gx = tx0 + cc - 1;
        float val = 0.f;
        if (gy >= 0 && gy < 64 && gx >= 0 && gx < 64)
            val = mid[((size_t)bb * CMID + (cib + ci)) * NPX + gy * 64 + gx];
        mt[idx] = val;
    }
    __syncthreads();
    int px = tid & 63;
    int su = __builtin_amdgcn_readfirstlane(tid >> 6);   // subpos, wave-uniform
    int ty = px >> 3, tx = px & 7;
    float acc[25];
    #pragma unroll
    for (int k = 0; k < 25; ++k) acc[k] = 0.f;
    for (int ci = 0; ci < 16; ++ci) {
        float nb[9];
        #pragma unroll
        for (int dy = 0; dy < 3; ++dy)
            #pragma unroll
            for (int dx = 0; dx < 3; ++dx)
                nb[dy * 3 + dx] = mt[ci * 100 + (ty + dy) * 10 + (tx + dx)];
        #pragma unroll
        for (int k = 0; k < 25; ++k) {
            const float* wk = ew + ((size_t)(4 * k + su) * CMID + (cib + ci)) * 9;
            float a = acc[k];
            #pragma unroll
            for (int j = 0; j < 9; ++j) a += nb[j] * wk[j];
            acc[k] = a;
        }
    }
    int spx = (ty0 + ty) * 64 + (tx0 + tx);
    #pragma unroll
    for (int k = 0; k < 25; ++k)
        atomicAdd(&enc[((size_t)bb * CENC + 4 * k + su) * NPX + spx], acc[k]);
}

// K2b: BN + clamp + pow + softmax over 25 taps; write wn[lowpx][s][25].
// grid 128, block 256 = 64 px x 4 subpos-waves.
__global__ __launch_bounds__(256) void k2b_softmax(
    const float* __restrict__ enc,
    const float* __restrict__ g, const float* __restrict__ bt,
    const float* __restrict__ m, const float* __restrict__ var,
    const float* __restrict__ power_p,
    float* __restrict__ wn)
{
    int tid = threadIdx.x;
    int s = tid >> 6;
    int p = blockIdx.x * 64 + (tid & 63);
    int bb = p >> 12, sp = p & (NPX - 1);
    float pp = fmaxf(power_p[0], 1e-5f);
    float tv[25];
    float mx = -1e30f;
    #pragma unroll
    for (int k = 0; k < 25; ++k) {
        int co = 4 * k + s;
        float e = enc[((size_t)bb * CENC + co) * NPX + sp];
        float val = bn_apply(e, g[co], bt[co], m[co], var[co]);
        val = fmaxf(val, 1e-5f);
        float x = exp2f(pp * log2f(val));   // val^pp, val > 0
        tv[k] = x;
        mx = fmaxf(mx, x);
    }
    float sum = 0.f;
    #pragma unroll
    for (int k = 0; k < 25; ++k) {
        float e = expf(tv[k] - mx);
        tv[k] = e;
        sum += e;
    }
    float r = 1.0f / sum;
    float* op = wn + ((size_t)p * 4 + s) * 25;
    #pragma unroll
    for (int k = 0; k < 25; ++k) op[k] = tv[k] * r;
}

// K3: reassembly. grid (32 spatial, 16 ch-chunks), block 256 = 16x16 low-res px.
// Each thread: one low-res pixel, 100 softmax weights in VGPRs, loops 16 channels,
// produces the 2x2 output block per channel (two coalesced float2 stores).
__global__ __launch_bounds__(256, 2) void k3_carafe(
    const float* __restrict__ X, const float* __restrict__ wn,
    float* __restrict__ out)
{
    __shared__ float xt[16 * 400];   // 16 ch x 20x20 halo tile, 25.6 KB
    int tid = threadIdx.x;
    int bx = blockIdx.x;
    int bb = bx >> 4;
    int t = bx & 15;
    int ty0 = (t >> 2) * 16, tx0 = (t & 3) * 16;
    int c0 = blockIdx.y * 16;
    for (int idx = tid; idx < 6400; idx += 256) {
        int ch = idx / 400;
        int rem = idx - ch * 400;
        int r = rem / 20, cc = rem - r * 20;
        int gy = ty0 + r - 2, gx = tx0 + cc - 2;
        float val = 0.f;
        if (gy >= 0 && gy < 64 && gx >= 0 && gx < 64)
            val = X[((size_t)bb * C_IN + c0 + ch) * NPX + gy * 64 + gx];
        xt[idx] = val;
    }
    int ylq = tid >> 4, xlq = tid & 15;
    int yl = ty0 + ylq, xl = tx0 + xlq;
    float wv[100];
    const float4* wp = (const float4*)(wn + (size_t)(bb * NPX + yl * 64 + xl) * 100);
    #pragma unroll
    for (int i = 0; i < 25; ++i) ((float4*)wv)[i] = wp[i];
    __syncthreads();
    for (int ch = 0; ch < 16; ++ch) {
        float x[25];
        #pragma unroll
        for (int ki = 0; ki < 5; ++ki)
            #pragma unroll
            for (int kj = 0; kj < 5; ++kj)
                x[ki * 5 + kj] = xt[ch * 400 + (ylq + ki) * 20 + (xlq + kj)];
        float a0 = 0.f, a1 = 0.f, a2 = 0.f, a3 = 0.f;
        #pragma unroll
        for (int k = 0; k < 25; ++k) {
            a0 += wv[k]      * x[k];
            a1 += wv[25 + k] * x[k];
            a2 += wv[50 + k] * x[k];
            a3 += wv[75 + k] * x[k];
        }
        float* ob = out + ((size_t)(bb * C_IN + c0 + ch) * H2 + 2 * yl) * W2 + 2 * xl;
        *(float2*)ob        = make_float2(a0, a1);
        *(float2*)(ob + W2) = make_float2(a2, a3);
    }
}

extern "C" void kernel_launch(void* const* d_in, const int* in_sizes, int n_in,
                              void* d_out, int out_size, void* d_ws, size_t ws_size,
                              hipStream_t stream)
{
    const float* X  = (const float*)d_in[0];
    const float* cw = (const float*)d_in[1];
    const float* cg = (const float*)d_in[2];
    const float* cb = (const float*)d_in[3];
    const float* cm = (const float*)d_in[4];
    const float* cv = (const float*)d_in[5];
    const float* ew = (const float*)d_in[6];
    const float* eg = (const float*)d_in[7];
    const float* eb = (const float*)d_in[8];
    const float* em = (const float*)d_in[9];
    const float* ev = (const float*)d_in[10];
    const float* pp = (const float*)d_in[11];
    float* out = (float*)d_out;

    float* ws  = (float*)d_ws;
    float* mid = ws;                        // 2*64*4096   = 524288 floats
    float* enc = ws + 524288;               // 2*100*4096  = 819200 floats
    float* wn  = ws + 524288 + 819200;      // 2*4096*4*25 = 819200 floats

    hipMemsetAsync(enc, 0, 819200 * sizeof(float), stream);
    k1_conv1x1<<<dim3(128, 2), 256, 0, stream>>>(X, cw, cg, cb, cm, cv, mid);
    k2a_conv3x3<<<dim3(128, 4), 256, 0, stream>>>(mid, ew, enc);
    k2b_softmax<<<dim3(128), 256, 0, stream>>>(enc, eg, eb, em, ev, pp, wn);
    k3_carafe<<<dim3(32, 16), 256, 0, stream>>>(X, wn, out);
}